// Round 1
// 70.401 us; speedup vs baseline: 1.0026x; 1.0026x over previous
//
#include <hip/hip_runtime.h>

// inter[b,u,i,d] = user[b,u,d]*img[b,i,d]; out_user = sum_i, out_img = sum_u.
//   user: [B=32, U=128, D=256] fp32,  img: [B=32, I=256, D=256] fp32
//   out = concat(out_user [B,U,D], out_img [B,I,D]) flat fp32
//
// Single fused kernel, no workspace, no second launch, no cross-block deps:
//  - 384 blocks = 12 units/batch (4 user 32-row chunks + 8 img 32-row chunks).
//  - Each block loads its own 32x256 chunk into registers (read once from HBM),
//    redundantly column-sums the opposing matrix of its batch (coalesced row
//    loads, split across the 4 waves, LDS-combined), then multiplies + stores.
//  - XCD swizzle: xcd = blk&7 owns 4 *complete* batches -> per-XCD L2 working
//    set = 4 * 384KB = 1.5MB (fits 4MiB L2), so the 12x-redundant opposing
//    reads are local-L2 hits, HBM sees each input byte once.
#define B 32
#define U 128
#define I 256
#define D 256

__global__ void __launch_bounds__(256) fused_interaction_kernel(
    const float* __restrict__ user,
    const float* __restrict__ img,
    float* __restrict__ out) {
  constexpr int U4b = U * D / 4;   // 8192  float4 per batch (user)
  constexpr int I4b = I * D / 4;   // 16384 float4 per batch (img)
  constexpr int NU4 = B * U4b;     // 262144 float4 (user section of out)

  __shared__ float4 part[4][64];

  // blk -> unit so that XCD (blk&7) gets 48 consecutive units = 4 full batches.
  const int blk  = blockIdx.x;
  const int unit = (blk & 7) * 48 + (blk >> 3);   // 0..383
  const int b    = unit / 12;
  const int j    = unit - b * 12;                  // 0..11 within batch

  const int tid  = threadIdx.x;
  const int rg   = tid >> 6;    // wave 0..3
  const int lane = tid & 63;    // float4 column 0..63

  const float4* u4 = (const float4*)user;
  const float4* i4 = (const float4*)img;
  float4* o4 = (float4*)out;

  const bool isUser = (j < 4);
  const int  c      = isUser ? j : (j - 4);        // 32-row chunk index

  // own chunk: 32 rows x 64 float4, contiguous
  const size_t ownBase = (isUser ? (size_t)b * U4b : (size_t)b * I4b)
                       + (size_t)c * 32 * 64;
  const float4* own = (isUser ? u4 : i4) + ownBase;
  float4* dst = o4 + (isUser ? ownBase : (size_t)NU4 + ownBase);

  // Issue own-chunk loads early; they complete under the sum loop below.
  float4 v[8];
  #pragma unroll
  for (int it = 0; it < 8; ++it)
    v[it] = own[(size_t)(rg * 8 + it) * 64 + lane];

  // Redundant column-sum of the opposing matrix (rows split across 4 waves).
  // Wave reads are full 1KB contiguous rows (lane = float4 column) -> coalesced.
  float4 acc = make_float4(0.f, 0.f, 0.f, 0.f);
  if (isUser) {
    const float4* opp = i4 + (size_t)b * I4b;      // img[b]: 256 rows
    #pragma unroll 16
    for (int r = rg * 64; r < rg * 64 + 64; ++r) {
      const float4 t = opp[(size_t)r * 64 + lane];
      acc.x += t.x; acc.y += t.y; acc.z += t.z; acc.w += t.w;
    }
  } else {
    const float4* opp = u4 + (size_t)b * U4b;      // user[b]: 128 rows
    #pragma unroll 16
    for (int r = rg * 32; r < rg * 32 + 32; ++r) {
      const float4 t = opp[(size_t)r * 64 + lane];
      acc.x += t.x; acc.y += t.y; acc.z += t.z; acc.w += t.w;
    }
  }
  part[rg][lane] = acc;
  __syncthreads();
  const float4 p0 = part[0][lane];
  const float4 p1 = part[1][lane];
  const float4 p2 = part[2][lane];
  const float4 p3 = part[3][lane];
  const float4 s  = make_float4(p0.x + p1.x + p2.x + p3.x,
                                p0.y + p1.y + p2.y + p3.y,
                                p0.z + p1.z + p2.z + p3.z,
                                p0.w + p1.w + p2.w + p3.w);

  #pragma unroll
  for (int it = 0; it < 8; ++it) {
    const float4 r = v[it];
    dst[(size_t)(rg * 8 + it) * 64 + lane] =
        make_float4(r.x * s.x, r.y * s.y, r.z * s.z, r.w * s.w);
  }
}

extern "C" void kernel_launch(void* const* d_in, const int* in_sizes, int n_in,
                              void* d_out, int out_size, void* d_ws, size_t ws_size,
                              hipStream_t stream) {
  const float* user = (const float*)d_in[0];
  const float* img  = (const float*)d_in[1];
  float* out = (float*)d_out;
  (void)d_ws; (void)ws_size;

  fused_interaction_kernel<<<dim3(384), dim3(256), 0, stream>>>(user, img, out);
}